// Round 3
// baseline (2202.010 us; speedup 1.0000x reference)
//
#include <hip/hip_runtime.h>

// Orthonorm: Y = X * (sqrt(512) * inv(chol(X^T X + eps I))^T)
// X: [262144, 512] fp32.  Heavy matmuls via bf16 MFMA (fp32 accum).
// Fast path: X -> bf16 once; gram + ymm read bf16; ymm stages via
// global_load_lds with pre-swizzled sources; chol chain: 64-wide register
// panels + blocked triangular inverse (dinv64 + tri_assemble GEMMs).
// MFMA operand-swapped (mfma(B,A)) so C-reg axis = contiguous dim -> float4 C.

#define EPSJ 1e-6f
#define SQRTD 22.627416997969522f

typedef short bf16x8 __attribute__((ext_vector_type(8)));
typedef float f32x4 __attribute__((ext_vector_type(4)));

__device__ __forceinline__ unsigned short f2bf(float f) {
  unsigned u = __float_as_uint(f);
  unsigned r = u + 0x7fffu + ((u >> 16) & 1u);   // RNE
  return (unsigned short)(r >> 16);
}

// 16B-slot XOR swizzle within a 128B LDS row (8 slots). Involution in slot.
__device__ __forceinline__ int swz(int row, int slot) {
  return slot ^ ((row ^ (row >> 3)) & 7);
}

__device__ __forceinline__ float wred(float s) {
  s += __shfl_xor(s, 1);  s += __shfl_xor(s, 2);  s += __shfl_xor(s, 4);
  s += __shfl_xor(s, 8);  s += __shfl_xor(s, 16); s += __shfl_xor(s, 32);
  return s;
}

#define GLOAD16(g, l)                                                         \
  __builtin_amdgcn_global_load_lds(                                           \
      (const __attribute__((address_space(1))) void*)(g),                     \
      (__attribute__((address_space(3))) void*)(l), 16, 0, 0)

// ---------------------------------------------------------------------------
// Kernel 0 (fast path): X fp32 -> Xbf bf16.  grid 2048 x 256.
// ---------------------------------------------------------------------------
__global__ void convert_bf(const float* __restrict__ X,
                           unsigned short* __restrict__ Xbf) {
  long idx = (long)blockIdx.x * blockDim.x + threadIdx.x;
  const long stride = (long)gridDim.x * blockDim.x;
  const long nch = 134217728 / 8;
  for (long i = idx; i < nch; i += stride) {
    float4 f0 = ((const float4*)X)[i * 2];
    float4 f1 = ((const float4*)X)[i * 2 + 1];
    uint4 o;
    o.x = (unsigned)f2bf(f0.x) | ((unsigned)f2bf(f0.y) << 16);
    o.y = (unsigned)f2bf(f0.z) | ((unsigned)f2bf(f0.w) << 16);
    o.z = (unsigned)f2bf(f1.x) | ((unsigned)f2bf(f1.y) << 16);
    o.w = (unsigned)f2bf(f1.z) | ((unsigned)f2bf(f1.w) << 16);
    ((uint4*)Xbf)[i] = o;
  }
}

// ---------------------------------------------------------------------------
// Kernel 1 (fast path): Gram partials from bf16 X. grid = 3*nchunk x 512.
// pos = b%3: (0,0),(256,256),(0,256) 256x256 tiles; LDS [c][k] swizzled,
// built by paired-row b32 pack writes.  MFMA operand-swapped; float4 stores.
// ---------------------------------------------------------------------------
__device__ __forceinline__ void stage_pack(const unsigned short* __restrict__ src,
                                           unsigned short* dst, int c0, int k) {
  uint4 a = *(const uint4*)src;          // row k,   cols c0..c0+7
  uint4 b = *(const uint4*)(src + 512);  // row k+1
  unsigned av[4] = {a.x, a.y, a.z, a.w}, bv[4] = {b.x, b.y, b.z, b.w};
  int k7 = (k & 7) * 2, khi = k >> 3;
  #pragma unroll
  for (int j = 0; j < 4; ++j) {
    int cA = c0 + 2 * j, cB = cA + 1;
    unsigned lo = (av[j] & 0xFFFFu) | (bv[j] << 16);
    unsigned hi = (av[j] >> 16) | (bv[j] & 0xFFFF0000u);
    int slA = khi ^ ((cA ^ (cA >> 3)) & 7);
    int slB = khi ^ ((cB ^ (cB >> 3)) & 7);
    *(unsigned*)((char*)dst + cA * 128 + slA * 16 + k7) = lo;
    *(unsigned*)((char*)dst + cB * 128 + slB * 16 + k7) = hi;
  }
}

__global__ __launch_bounds__(512, 2) void gram_bf(
    const unsigned short* __restrict__ Xbf, float* __restrict__ part,
    int nchunk) {
  __shared__ unsigned short As[256 * 64];
  __shared__ unsigned short Bs[256 * 64];
  const int b = blockIdx.x, pos = b % 3, chunk = b / 3;
  const int s0 = (int)((long)4096 * chunk / nchunk);
  const int s1 = (int)((long)4096 * (chunk + 1) / nchunk);
  const int ca = (pos == 1) ? 256 : 0;
  const int cb2 = (pos == 0) ? 0 : 256;
  const bool diag = (pos != 2);
  const int t = threadIdx.x, lane = t & 63, w = t >> 6;
  const int wr = w >> 2, wc = w & 3;

  f32x4 acc[8][4];
  const f32x4 zf = {0.f, 0.f, 0.f, 0.f};
  #pragma unroll
  for (int a = 0; a < 8; ++a)
    #pragma unroll
    for (int bb = 0; bb < 4; ++bb) acc[a][bb] = zf;

  const int c0 = (t & 31) * 8;   // relative col octet
  const int kp = t >> 5;         // 0..15

  for (int ks = s0; ks < s1; ++ks) {
    long rb = (long)ks * 64;
    #pragma unroll
    for (int it = 0; it < 2; ++it) {
      int k = it * 32 + kp * 2;
      long r = rb + k;
      stage_pack(Xbf + r * 512 + ca + c0, As, c0, k);
      if (!diag) stage_pack(Xbf + r * 512 + cb2 + c0, Bs, c0, k);
    }
    __syncthreads();
    const unsigned short* Bp = diag ? As : Bs;
    #pragma unroll
    for (int kk = 0; kk < 2; ++kk) {
      bf16x8 af[8], bfr[4];
      #pragma unroll
      for (int fm = 0; fm < 8; ++fm) {
        int row = wr * 128 + fm * 16 + (lane & 15);
        int slot = swz(row, kk * 4 + (lane >> 4));
        af[fm] = *(const bf16x8*)((const char*)As + row * 128 + slot * 16);
      }
      #pragma unroll
      for (int fn = 0; fn < 4; ++fn) {
        int row = wc * 64 + fn * 16 + (lane & 15);
        int slot = swz(row, kk * 4 + (lane >> 4));
        bfr[fn] = *(const bf16x8*)((const char*)Bp + row * 128 + slot * 16);
      }
      #pragma unroll
      for (int fm = 0; fm < 8; ++fm)
        #pragma unroll
        for (int fn = 0; fn < 4; ++fn)
          acc[fm][fn] = __builtin_amdgcn_mfma_f32_16x16x32_bf16(
              bfr[fn], af[fm], acc[fm][fn], 0, 0, 0);   // swapped: reg axis = n
    }
    __syncthreads();
  }
  float* out = part + (long)b * 65536;
  #pragma unroll
  for (int fm = 0; fm < 8; ++fm)
    #pragma unroll
    for (int fn = 0; fn < 4; ++fn) {
      int mi = wr * 128 + fm * 16 + (lane & 15);
      int nj = wc * 64 + fn * 16 + (lane >> 4) * 4;
      *(float4*)(out + mi * 256 + nj) = *(float4*)&acc[fm][fn];
    }
}

// ---------------------------------------------------------------------------
// Kernel 1b (fallback): Gram partials from fp32 X (round-1 version).
// ---------------------------------------------------------------------------
__global__ __launch_bounds__(512, 2) void gram_f32(
    const float* __restrict__ X, float* __restrict__ part, int nchunk) {
  __shared__ unsigned short As[256 * 64];
  __shared__ unsigned short Bs[256 * 64];
  const int b = blockIdx.x;
  const int pos = b % 3;
  const int chunk = b / 3;
  const int CR = 262144 / nchunk;
  const long r0 = (long)chunk * CR;
  const int ca = (pos == 1) ? 256 : 0;
  const int cb = (pos == 0) ? 0 : 256;
  const bool diag = (pos != 2);
  const int t = threadIdx.x, lane = t & 63, w = t >> 6;
  const int wr = w >> 2, wc = w & 3;

  f32x4 acc[8][4];
  const f32x4 zf = {0.f, 0.f, 0.f, 0.f};
  #pragma unroll
  for (int a = 0; a < 8; ++a)
    #pragma unroll
    for (int bb = 0; bb < 4; ++bb) acc[a][bb] = zf;

  const int c_oct = t & 31, msub = t >> 5;

  for (int ks = 0; ks < CR; ks += 64) {
    #pragma unroll
    for (int it = 0; it < 4; ++it) {
      int m = msub + 16 * it;
      long row = r0 + ks + m;
      const float4* sa = (const float4*)(X + row * 512 + ca + c_oct * 8);
      float4 a0 = sa[0], a1 = sa[1];
      {
        float v[8] = {a0.x, a0.y, a0.z, a0.w, a1.x, a1.y, a1.z, a1.w};
        #pragma unroll
        for (int s = 0; s < 8; ++s) {
          int c = c_oct * 8 + s;
          int off = c * 128 + ((2 * m) ^ (((c ^ (c >> 3)) & 7) << 4));
          *(unsigned short*)((char*)As + off) = f2bf(v[s]);
        }
      }
      if (!diag) {
        const float4* sb = (const float4*)(X + row * 512 + cb + c_oct * 8);
        float4 b0 = sb[0], b1 = sb[1];
        float v[8] = {b0.x, b0.y, b0.z, b0.w, b1.x, b1.y, b1.z, b1.w};
        #pragma unroll
        for (int s = 0; s < 8; ++s) {
          int c = c_oct * 8 + s;
          int off = c * 128 + ((2 * m) ^ (((c ^ (c >> 3)) & 7) << 4));
          *(unsigned short*)((char*)Bs + off) = f2bf(v[s]);
        }
      }
    }
    __syncthreads();
    const unsigned short* Bp = diag ? As : Bs;
    #pragma unroll
    for (int kk = 0; kk < 2; ++kk) {
      bf16x8 af[8], bfr[4];
      #pragma unroll
      for (int fm = 0; fm < 8; ++fm) {
        int row = wr * 128 + fm * 16 + (lane & 15);
        int slot = swz(row, kk * 4 + (lane >> 4));
        af[fm] = *(const bf16x8*)((const char*)As + row * 128 + slot * 16);
      }
      #pragma unroll
      for (int fn = 0; fn < 4; ++fn) {
        int row = wc * 64 + fn * 16 + (lane & 15);
        int slot = swz(row, kk * 4 + (lane >> 4));
        bfr[fn] = *(const bf16x8*)((const char*)Bp + row * 128 + slot * 16);
      }
      #pragma unroll
      for (int fm = 0; fm < 8; ++fm)
        #pragma unroll
        for (int fn = 0; fn < 4; ++fn)
          acc[fm][fn] = __builtin_amdgcn_mfma_f32_16x16x32_bf16(
              af[fm], bfr[fn], acc[fm][fn], 0, 0, 0);
    }
    __syncthreads();
  }
  float* out = part + (long)b * 65536;
  #pragma unroll
  for (int fm = 0; fm < 8; ++fm)
    #pragma unroll
    for (int fn = 0; fn < 4; ++fn)
      #pragma unroll
      for (int j = 0; j < 4; ++j) {
        int i  = wr * 128 + fm * 16 + (lane >> 4) * 4 + j;
        int jj = wc * 64 + fn * 16 + (lane & 15);
        out[i * 256 + jj] = acc[fm][fn][j];
      }
}

// ---------------------------------------------------------------------------
// Kernel 2: reduce partials -> full symmetric G [512][512] fp32. grid 768x256
// (partials layout is [m][n] in both gram variants)
// ---------------------------------------------------------------------------
__global__ void gram_reduce(const float* __restrict__ part,
                            float* __restrict__ G, int nchunk) {
  int idx = blockIdx.x * 256 + threadIdx.x;   // < 196608
  int pos = idx >> 16;
  int e = idx & 65535;
  float s = 0.f;
  for (int ch = 0; ch < nchunk; ++ch)
    s += part[(long)(ch * 3 + pos) * 65536 + e];
  int i = e >> 8, j = e & 255;
  if (pos == 0) {
    G[i * 512 + j] = s;
  } else if (pos == 1) {
    G[(256 + i) * 512 + 256 + j] = s;
  } else {
    G[i * 512 + 256 + j] = s;
    G[(256 + j) * 512 + i] = s;
  }
}

// ---------------------------------------------------------------------------
// Kernel 3: factor 128x128 diagonal block at (c0,c0) in place (lower L).
// Two 64-wide sub-panels: full-wave register factor (wave0), one 64-row
// thread-per-row solve, one 4x2-register-tiled trailing update.
// NOTE: strict upper of the block is left stale -- never read downstream.
// ---------------------------------------------------------------------------
__global__ __launch_bounds__(512) void chol_diag(float* __restrict__ G, int c0) {
  __shared__ float P[128][129];
  int t = threadIdx.x;
  for (int idx = t; idx < 128 * 128; idx += 512) {
    int i = idx >> 7, j = idx & 127;
    float v = G[(long)(c0 + i) * 512 + c0 + j];
    if (i == j) v += EPSJ;
    P[i][j] = v;
  }
  __syncthreads();
  int lane = t & 63, w = t >> 6;
  #pragma unroll
  for (int sp = 0; sp < 2; ++sp) {
    int b0 = sp * 64;
    if (w == 0) {
      float r[64];
      #pragma unroll
      for (int k = 0; k < 64; ++k) r[k] = P[b0 + lane][b0 + k];
      #pragma unroll
      for (int j = 0; j < 64; ++j) {
        float d = sqrtf(__shfl(r[j], j));
        if (lane == j) r[j] = d;
        else if (lane > j) r[j] = r[j] / d;
        float rj = r[j];
        #pragma unroll
        for (int k = j + 1; k < 64; ++k) {
          float Lkj = __shfl(rj, k);
          if (lane > j) r[k] -= rj * Lkj;
        }
      }
      #pragma unroll
      for (int k = 0; k < 64; ++k) P[b0 + lane][b0 + k] = r[k];
    }
    __syncthreads();
    if (sp == 0) {
      if (t < 64) {            // solve rows 64..127 against L[0:64,0:64]
        int rr = 64 + t;
        float x[64];
        #pragma unroll
        for (int j = 0; j < 64; ++j) x[j] = P[rr][j];
        #pragma unroll
        for (int j = 0; j < 64; ++j) {
          float xj = x[j] / P[j][j];
          x[j] = xj;
          #pragma unroll
          for (int k2 = j + 1; k2 < 64; ++k2) x[k2] -= xj * P[k2][j];
        }
        #pragma unroll
        for (int j = 0; j < 64; ++j) P[rr][j] = x[j];
      }
      __syncthreads();
      // trailing update P[64+,64+] -= S S^T  (S = P[64+][0:64]); 4x2 tiles
      int or_ = (t >> 5) * 4;    // 16 row-groups
      int oc = (t & 31) * 2;     // 32 col-pairs
      float cc[4][2] = {{0,0},{0,0},{0,0},{0,0}};
      for (int k = 0; k < 64; ++k) {
        float a0 = P[64 + or_][k],     a1 = P[64 + or_ + 1][k];
        float a2 = P[64 + or_ + 2][k], a3 = P[64 + or_ + 3][k];
        float e0 = P[64 + oc][k],      e1 = P[64 + oc + 1][k];
        cc[0][0] += a0 * e0; cc[0][1] += a0 * e1;
        cc[1][0] += a1 * e0; cc[1][1] += a1 * e1;
        cc[2][0] += a2 * e0; cc[2][1] += a2 * e1;
        cc[3][0] += a3 * e0; cc[3][1] += a3 * e1;
      }
      // writes go to cols >=64, reads were cols <64: disjoint, no barrier
      #pragma unroll
      for (int u = 0; u < 4; ++u) {
        P[64 + or_ + u][64 + oc]     -= cc[u][0];
        P[64 + or_ + u][64 + oc + 1] -= cc[u][1];
      }
      __syncthreads();
    }
  }
  __syncthreads();
  for (int idx = t; idx < 128 * 128; idx += 512) {
    int i = idx >> 7, j = idx & 127;
    G[(long)(c0 + i) * 512 + c0 + j] = P[i][j];
  }
}

// ---------------------------------------------------------------------------
// Kernel 4: panel solve (wave-per-row forward substitution). grid R/4 x 256.
// ---------------------------------------------------------------------------
__global__ void chol_solve(float* __restrict__ G, int p) {
  int c0 = 128 * p;
  int row0 = c0 + 128;
  int w = threadIdx.x >> 6, lane = threadIdx.x & 63;
  long r = row0 + blockIdx.x * 4 + w;
  float x[2];
  x[0] = G[r * 512 + c0 + lane];
  x[1] = G[r * 512 + c0 + 64 + lane];
  #pragma unroll
  for (int q = 0; q < 2; ++q) {
    for (int ii = 0; ii < 64; ++ii) {
      int i = q * 64 + ii;
      const float* Lrow = G + (long)(c0 + i) * 512 + c0;
      float s = 0.f;
      if (q == 1) s += x[0] * Lrow[lane];
      s += (lane < ii) ? x[q] * Lrow[q * 64 + lane] : 0.f;
      s = wred(s);
      float ai = __shfl(x[q], ii);
      float xi = (ai - s) / Lrow[i];
      if (lane == ii) x[q] = xi;
    }
  }
  G[r * 512 + c0 + lane] = x[0];
  G[r * 512 + c0 + 64 + lane] = x[1];
}

// ---------------------------------------------------------------------------
// Kernel 5: SYRK trailing update A22 -= L21 L21^T, 64x64 lower tiles, fp32.
// ---------------------------------------------------------------------------
__global__ void chol_syrk(float* __restrict__ G, int t0) {
  int id = blockIdx.x;
  int ti = 0;
  while ((ti + 1) * (ti + 2) / 2 <= id) ++ti;
  int tj = id - ti * (ti + 1) / 2;
  __shared__ float As2[64][130], Bs2[64][130];
  int t = threadIdx.x;
  int c0 = t0 - 128;
  for (int idx = t; idx < 64 * 128; idx += 256) {
    int i = idx >> 7, j = idx & 127;
    As2[i][j] = G[(long)(t0 + 64 * ti + i) * 512 + c0 + j];
    Bs2[i][j] = G[(long)(t0 + 64 * tj + i) * 512 + c0 + j];
  }
  __syncthreads();
  int tr = (t >> 4) * 4, tc = (t & 15) * 4;
  float cacc[4][4];
  #pragma unroll
  for (int u = 0; u < 4; ++u)
    #pragma unroll
    for (int v = 0; v < 4; ++v) cacc[u][v] = 0.f;
  for (int k = 0; k < 128; ++k) {
    float a4[4], b4[4];
    #pragma unroll
    for (int u = 0; u < 4; ++u) { a4[u] = As2[tr + u][k]; b4[u] = Bs2[tc + u][k]; }
    #pragma unroll
    for (int u = 0; u < 4; ++u)
      #pragma unroll
      for (int v = 0; v < 4; ++v) cacc[u][v] += a4[u] * b4[v];
  }
  #pragma unroll
  for (int u = 0; u < 4; ++u)
    #pragma unroll
    for (int v = 0; v < 4; ++v)
      G[(long)(t0 + 64 * ti + tr + u) * 512 + t0 + 64 * tj + tc + v] -= cacc[u][v];
}

// ---------------------------------------------------------------------------
// Kernel 6a: invert the 8 diagonal 64x64 blocks of L (exact zeros above diag).
// grid 8 x 64 (one wave per block).  Dinv[p] is 64x64 row-major fp32.
// ---------------------------------------------------------------------------
__global__ __launch_bounds__(64) void dinv64(const float* __restrict__ G,
                                             float* __restrict__ Dinv) {
  __shared__ float Lb[64][65];
  int p = blockIdx.x;
  int lane = threadIdx.x;
  for (int i = 0; i < 64; ++i)
    Lb[i][lane] = (lane <= i) ? G[(long)(64 * p + i) * 512 + 64 * p + lane] : 0.f;
  __syncthreads();
  float x[64];   // column `lane` of the inverse
  #pragma unroll
  for (int i = 0; i < 64; ++i) {
    float s = (i == lane) ? 1.f : 0.f;
    #pragma unroll
    for (int j = 0; j < i; ++j) s -= Lb[i][j] * x[j];
    x[i] = s / Lb[i][i];
  }
  #pragma unroll
  for (int i = 0; i < 64; ++i)
    Dinv[p * 4096 + i * 64 + lane] = x[i];
}

// ---------------------------------------------------------------------------
// Kernel 6b: blocked back-substitution, one workgroup per 64-wide column
// block q of Linv: B_p = -Dinv_p * sum_{r=q}^{p-1} L[p,r] B_r  (B_q = Dinv_q).
// Emits Wt[n][k] = sqrt(512)*Linv[n][k] in bf16, slot-pre-swizzled for ymm2,
// plus zeros for the upper triangle.  grid 8 x 256.
// ---------------------------------------------------------------------------
__global__ __launch_bounds__(256) void tri_assemble(
    const float* __restrict__ G, const float* __restrict__ Dinv,
    unsigned short* __restrict__ Wt) {
  __shared__ float Bsh[448 * 64];   // rows for p>q, 112 KB
  __shared__ float T[64 * 64];      // 16 KB
  const int q = blockIdx.x, t = threadIdx.x;
  const int or_ = (t >> 4) * 4, oc = (t & 15) * 4;

  for (int p = q + 1; p < 8; ++p) {
    float cc[4][4] = {{0}};
    for (int r = q; r < p; ++r) {
      const float* Lbase = G + (long)(64 * p) * 512 + 64 * r;
      #pragma unroll 4
      for (int k = 0; k < 64; ++k) {
        float a0 = Lbase[(or_ + 0) * 512 + k];
        float a1 = Lbase[(or_ + 1) * 512 + k];
        float a2 = Lbase[(or_ + 2) * 512 + k];
        float a3 = Lbase[(or_ + 3) * 512 + k];
        float b0, b1, b2, b3;
        if (r == q) {
          const float* Bq = Dinv + q * 4096 + k * 64 + oc;
          b0 = Bq[0]; b1 = Bq[1]; b2 = Bq[2]; b3 = Bq[3];
        } else {
          const float* Br = Bsh + ((r - q - 1) * 64 + k) * 64 + oc;
          b0 = Br[0]; b1 = Br[1]; b2 = Br[2]; b3 = Br[3];
        }
        cc[0][0] += a0*b0; cc[0][1] += a0*b1; cc[0][2] += a0*b2; cc[0][3] += a0*b3;
        cc[1][0] += a1*b0; cc[1][1] += a1*b1; cc[1][2] += a1*b2; cc[1][3] += a1*b3;
        cc[2][0] += a2*b0; cc[2][1] += a2*b1; cc[2][2] += a2*b2; cc[2][3] += a2*b3;
        cc[3][0] += a3*b0; cc[3][1] += a3*b1; cc[3][2] += a3*b2; cc[3][3] += a3*b3;
      }
    }
    #pragma unroll
    for (int u = 0; u < 4; ++u)
      #pragma unroll
      for (int v = 0; v < 4; ++v)
        T[(or_ + u) * 64 + oc + v] = cc[u][v];
    __syncthreads();

    float c2[4][4] = {{0}};
    const float* Dp = Dinv + p * 4096;
    #pragma unroll 4
    for (int k = 0; k < 64; ++k) {
      float a0 = Dp[(or_ + 0) * 64 + k];
      float a1 = Dp[(or_ + 1) * 64 + k];
      float a2 = Dp[(or_ + 2) * 64 + k];
      float a3 = Dp[(or_ + 3) * 64 + k];
      const float* Tk = T + k * 64 + oc;
      float b0 = Tk[0], b1 = Tk[1], b2 = Tk[2], b3 = Tk[3];
      c2[0][0] += a0*b0; c2[0][1] += a0*b1; c2[0][2] += a0*b2; c2[0][3] += a0*b3;
      c2[1][0] += a1*b0; c2[1][1] += a1*b1; c2[1][2] += a1*b2; c2[1][3] += a1*b3;
      c2[2][0] += a2*b0; c2[2][1] += a2*b1; c2[2][2] += a2*b2; c2[2][3] += a2*b3;
      c2[3][0] += a3*b0; c2[3][1] += a3*b1; c2[3][2] += a3*b2; c2[3][3] += a3*b3;
    }
    #pragma unroll
    for (int u = 0; u < 4; ++u)
      #pragma unroll
      for (int v = 0; v < 4; ++v)
        Bsh[((p - q - 1) * 64 + or_ + u) * 64 + oc + v] = -c2[u][v];
    __syncthreads();
  }

  // emit Wt column-block q (cols 64q..64q+63), slot-swizzled bf16
  const int nr = (8 - q) * 64;
  for (int idx = t; idx < nr * 64; idx += 256) {
    int i = idx >> 6, kk = idx & 63;
    float v = (i < 64) ? Dinv[q * 4096 + i * 64 + kk]
                       : Bsh[(i - 64) * 64 + kk];
    int n = 64 * q + i;
    int sl = (kk >> 3) ^ ((n ^ (n >> 3)) & 7);
    Wt[(long)n * 512 + 64 * q + sl * 8 + (kk & 7)] = f2bf(SQRTD * v);
  }
  for (int idx = t; idx < 64 * q * 64; idx += 256) {   // zeros above diagonal
    int n = idx >> 6, kk = idx & 63;
    Wt[(long)n * 512 + 64 * q + kk] = 0;
  }
}

// ---------------------------------------------------------------------------
// Kernel 6c (fallback): wave-per-column triangular inverse, plain Wt layout.
// ---------------------------------------------------------------------------
__global__ void tri_inv(const float* __restrict__ G,
                        unsigned short* __restrict__ Wt) {
  int w = threadIdx.x >> 6, lane = threadIdx.x & 63;
  int c = blockIdx.x * 4 + w;
  float v8[8];
  #pragma unroll
  for (int q = 0; q < 8; ++q) v8[q] = 0.f;
  #pragma unroll
  for (int q = 0; q < 8; ++q) {
    for (int ii = 0; ii < 64; ++ii) {
      int i = q * 64 + ii;
      const float* Lrow = G + (long)i * 512;
      float s = 0.f;
      #pragma unroll
      for (int qq = 0; qq < 8; ++qq) {
        if (qq < q) s += v8[qq] * Lrow[qq * 64 + lane];
      }
      s += (lane < ii) ? v8[q] * Lrow[q * 64 + lane] : 0.f;
      s = wred(s);
      float xi = (((i == c) ? 1.f : 0.f) - s) / Lrow[i];
      if (lane == ii) v8[q] = xi;
    }
  }
  #pragma unroll
  for (int q = 0; q < 8; ++q) {
    int i = q * 64 + lane;
    Wt[(long)i * 512 + c] = f2bf(SQRTD * v8[q]);
  }
}

// ---------------------------------------------------------------------------
// Kernel 7 (fast path): Y = Xbf @ W via global_load_lds staging, dbuf 2-phase.
// grid (4 n, 2048 m) x 256.  MFMA operand-swapped -> float4 C stores.
// ---------------------------------------------------------------------------
__global__ __launch_bounds__(256, 2) void ymm2(
    const unsigned short* __restrict__ Xbf,
    const unsigned short* __restrict__ Wt, float* __restrict__ Y) {
  __shared__ unsigned short As[2][128 * 64];
  __shared__ unsigned short Bs[2][128 * 64];
  const int t = threadIdx.x, lane = t & 63, w = t >> 6;
  const long m0 = (long)blockIdx.y * 128;
  const int n0 = blockIdx.x * 128;
  const int wm = (w >> 1) * 64, wn = (w & 1) * 64;
  const int lrow = lane >> 3, lslot = lane & 7;
  f32x4 acc[4][4];
  const f32x4 zf = {0.f, 0.f, 0.f, 0.f};
  #pragma unroll
  for (int a = 0; a < 4; ++a)
    #pragma unroll
    for (int bq = 0; bq < 4; ++bq) acc[a][bq] = zf;

  auto stage = [&](int buf, int k0) {
    #pragma unroll
    for (int j = 0; j < 4; ++j) {
      int row = (w * 4 + j) * 8 + lrow;
      const unsigned short* sA =
          Xbf + (m0 + row) * 512 + k0 + swz(row, lslot) * 8;
      const unsigned short* sB =
          Wt + (long)(n0 + row) * 512 + k0 + lslot * 8;
      GLOAD16(sA, &As[buf][(w * 4 + j) * 512]);
      GLOAD16(sB, &Bs[buf][(w * 4 + j) * 512]);
    }
  };
  auto compute = [&](int buf) {
    #pragma unroll
    for (int kk = 0; kk < 2; ++kk) {
      bf16x8 af[4], bfr[4];
      #pragma unroll
      for (int fm = 0; fm < 4; ++fm) {
        int row = wm + fm * 16 + (lane & 15);
        af[fm] = *(const bf16x8*)((const char*)As[buf] + row * 128 +
                                  swz(row, kk * 4 + (lane >> 4)) * 16);
      }
      #pragma unroll
      for (int fn = 0; fn < 4; ++fn) {
        int row = wn + fn * 16 + (lane & 15);
        bfr[fn] = *(const bf16x8*)((const char*)Bs[buf] + row * 128 +
                                   swz(row, kk * 4 + (lane >> 4)) * 16);
      }
      #pragma unroll
      for (int fm = 0; fm < 4; ++fm)
        #pragma unroll
        for (int fn = 0; fn < 4; ++fn)
          acc[fm][fn] = __builtin_amdgcn_mfma_f32_16x16x32_bf16(
              bfr[fn], af[fm], acc[fm][fn], 0, 0, 0);   // swapped
    }
  };

  stage(0, 0);
  __syncthreads();
  int cur = 0;
  #pragma unroll 1
  for (int kt = 0; kt < 7; ++kt) {
    stage(cur ^ 1, (kt + 1) * 64);
    compute(cur);
    __syncthreads();
    cur ^= 1;
  }
  compute(cur);

  #pragma unroll
  for (int fm = 0; fm < 4; ++fm)
    #pragma unroll
    for (int fn = 0; fn < 4; ++fn) {
      long row = m0 + wm + fm * 16 + (lane & 15);
      int col = n0 + wn + fn * 16 + (lane >> 4) * 4;
      *(float4*)(Y + row * 512 + col) = *(float4*)&acc[fm][fn];
    }
}

// ---------------------------------------------------------------------------
// Kernel 7b (fallback): round-1 ymm, fp32 X reg-staged.
// ---------------------------------------------------------------------------
__global__ __launch_bounds__(256) void ymm_v1(const float* __restrict__ X,
                                              const unsigned short* __restrict__ Wt,
                                              float* __restrict__ Y) {
  __shared__ unsigned short As[128 * 64];
  __shared__ unsigned short Bs[128 * 64];
  const int t = threadIdx.x, lane = t & 63, w = t >> 6;
  const long m0 = (long)blockIdx.x * 128;
  const int n0 = blockIdx.y * 128;
  const int wm = (w >> 1) * 64, wn = (w & 1) * 64;
  f32x4 acc[4][4];
  const f32x4 zf = {0.f, 0.f, 0.f, 0.f};
  #pragma unroll
  for (int a = 0; a < 4; ++a)
    #pragma unroll
    for (int bq = 0; bq < 4; ++bq) acc[a][bq] = zf;
  const int ko = t & 7, mrow = t >> 3;

  for (int k0 = 0; k0 < 512; k0 += 64) {
    #pragma unroll
    for (int it = 0; it < 4; ++it) {
      int m = mrow + 32 * it;
      const float4* src = (const float4*)(X + (m0 + m) * 512 + k0 + ko * 8);
      float4 f0 = src[0], f1 = src[1];
      unsigned p0 = (unsigned)f2bf(f0.x) | ((unsigned)f2bf(f0.y) << 16);
      unsigned p1 = (unsigned)f2bf(f0.z) | ((unsigned)f2bf(f0.w) << 16);
      unsigned p2 = (unsigned)f2bf(f1.x) | ((unsigned)f2bf(f1.y) << 16);
      unsigned p3 = (unsigned)f2bf(f1.z) | ((unsigned)f2bf(f1.w) << 16);
      int slot = swz(m, ko);
      *(uint4*)((char*)As + m * 128 + slot * 16) = make_uint4(p0, p1, p2, p3);
    }
    #pragma unroll
    for (int it = 0; it < 4; ++it) {
      int n = mrow + 32 * it;
      uint4 raw = *(const uint4*)(Wt + (long)(n0 + n) * 512 + k0 + ko * 8);
      int slot = swz(n, ko);
      *(uint4*)((char*)Bs + n * 128 + slot * 16) = raw;
    }
    __syncthreads();
    #pragma unroll
    for (int kk = 0; kk < 2; ++kk) {
      bf16x8 af[4], bfr[4];
      #pragma unroll
      for (int fm = 0; fm < 4; ++fm) {
        int row = wm + fm * 16 + (lane & 15);
        af[fm] = *(const bf16x8*)((const char*)As + row * 128 +
                                  swz(row, kk * 4 + (lane >> 4)) * 16);
      }
      #pragma unroll
      for (int fn = 0; fn < 4; ++fn) {
        int row = wn + fn * 16 + (lane & 15);
        bfr[fn] = *(const bf16x8*)((const char*)Bs + row * 128 +
                                   swz(row, kk * 4 + (lane >> 4)) * 16);
      }
      #pragma unroll
      for (int fm = 0; fm < 4; ++fm)
        #pragma unroll
        for (int fn = 0; fn < 4; ++fn)
          acc[fm][fn] = __builtin_amdgcn_mfma_f32_16x16x32_bf16(
              af[fm], bfr[fn], acc[fm][fn], 0, 0, 0);
    }
    __syncthreads();
  }
  #pragma unroll
  for (int fm = 0; fm < 4; ++fm)
    #pragma unroll
    for (int fn = 0; fn < 4; ++fn)
      #pragma unroll
      for (int j = 0; j < 4; ++j) {
        long row = m0 + wm + fm * 16 + (lane >> 4) * 4 + j;
        int col = n0 + wn + fn * 16 + (lane & 15);
        Y[row * 512 + col] = acc[fm][fn][j];
      }
}

// ---------------------------------------------------------------------------
static void chol_chain(float* G, hipStream_t stream) {
  for (int p = 0; p < 4; ++p) {
    chol_diag<<<1, 512, 0, stream>>>(G, 128 * p);
    if (p < 3) {
      int row0 = 128 * (p + 1);
      chol_solve<<<(512 - row0) / 4, 256, 0, stream>>>(G, p);
      int nt = (512 - row0) / 64;
      chol_syrk<<<nt * (nt + 1) / 2, 256, 0, stream>>>(G, row0);
    }
  }
}

extern "C" void kernel_launch(void* const* d_in, const int* in_sizes, int n_in,
                              void* d_out, int out_size, void* d_ws, size_t ws_size,
                              hipStream_t stream) {
  const float* X = (const float*)d_in[0];
  float* Y = (float*)d_out;
  char* ws = (char*)d_ws;
  float* G = (float*)ws;                                     // 1 MiB fp32
  unsigned short* Wt = (unsigned short*)(ws + (1 << 20));    // 512 KiB bf16
  float* Dinv = (float*)(ws + (1 << 20) + (1 << 19));        // 128 KiB fp32

  const int NCH_FAST = 85;
  size_t part_off = (size_t)(2 << 20);
  size_t part_bytes = (size_t)NCH_FAST * 3 * 65536 * 4;      // 66.8 MB
  size_t xbf_off = part_off + part_bytes;
  size_t need = xbf_off + (size_t)134217728 * 2;             // + 256 MiB

  if (ws_size >= need) {
    float* part = (float*)(ws + part_off);
    unsigned short* Xbf = (unsigned short*)(ws + xbf_off);
    convert_bf<<<2048, 256, 0, stream>>>(X, Xbf);
    gram_bf<<<3 * NCH_FAST, 512, 0, stream>>>(Xbf, part, NCH_FAST);
    gram_reduce<<<768, 256, 0, stream>>>(part, G, NCH_FAST);
    chol_chain(G, stream);
    dinv64<<<8, 64, 0, stream>>>(G, Dinv);
    tri_assemble<<<8, 256, 0, stream>>>(G, Dinv, Wt);
    ymm2<<<dim3(4, 2048), 256, 0, stream>>>(Xbf, Wt, Y);
  } else {
    float* part = (float*)(ws + (1 << 20) + (1 << 19));
    size_t fixed = (size_t)(1 << 20) + (1 << 19);
    int nchunk = 64;
    while (nchunk > 1 && fixed + (size_t)nchunk * 3 * 65536 * 4 > ws_size)
      nchunk >>= 1;
    gram_f32<<<3 * nchunk, 512, 0, stream>>>(X, part, nchunk);
    gram_reduce<<<768, 256, 0, stream>>>(part, G, nchunk);
    chol_chain(G, stream);
    tri_inv<<<128, 256, 0, stream>>>(G, Wt);
    ymm_v1<<<dim3(2048, 4), 256, 0, stream>>>(X, Wt, Y);
  }
}

// Round 4
// 1471.858 us; speedup vs baseline: 1.4961x; 1.4961x over previous
//
#include <hip/hip_runtime.h>

// Orthonorm: Y = X * (sqrt(512) * inv(chol(X^T X + eps I))^T)
// X: [262144, 512] fp32.  Heavy matmuls via bf16 MFMA (fp32 accum).
// Fast path: X -> bf16 once; gram + ymm read bf16; ymm stages via
// global_load_lds with pre-swizzled sources.
// Chol chain: left-looking NB=64 blocked factorization.  Serial parts use
// ONLY 32-element register arrays (496/528-body unrolls -- proven to stay in
// registers; 64-element versions spilled to scratch: round-3 post-mortem).
// Panel trsm is a GEMM against Dinv (no wave-serial substitution).

#define EPSJ 1e-6f
#define SQRTD 22.627416997969522f

typedef short bf16x8 __attribute__((ext_vector_type(8)));
typedef float f32x4 __attribute__((ext_vector_type(4)));

__device__ __forceinline__ unsigned short f2bf(float f) {
  unsigned u = __float_as_uint(f);
  unsigned r = u + 0x7fffu + ((u >> 16) & 1u);   // RNE
  return (unsigned short)(r >> 16);
}

// 16B-slot XOR swizzle within a 128B LDS row (8 slots). Involution in slot.
__device__ __forceinline__ int swz(int row, int slot) {
  return slot ^ ((row ^ (row >> 3)) & 7);
}

__device__ __forceinline__ float wred(float s) {
  s += __shfl_xor(s, 1);  s += __shfl_xor(s, 2);  s += __shfl_xor(s, 4);
  s += __shfl_xor(s, 8);  s += __shfl_xor(s, 16); s += __shfl_xor(s, 32);
  return s;
}

#define GLOAD16(g, l)                                                         \
  __builtin_amdgcn_global_load_lds(                                           \
      (const __attribute__((address_space(1))) void*)(g),                     \
      (__attribute__((address_space(3))) void*)(l), 16, 0, 0)

// ---------------------------------------------------------------------------
// Kernel 0 (fast path): X fp32 -> Xbf bf16.  grid 2048 x 256.
// ---------------------------------------------------------------------------
__global__ void convert_bf(const float* __restrict__ X,
                           unsigned short* __restrict__ Xbf) {
  long idx = (long)blockIdx.x * blockDim.x + threadIdx.x;
  const long stride = (long)gridDim.x * blockDim.x;
  const long nch = 134217728 / 8;
  for (long i = idx; i < nch; i += stride) {
    float4 f0 = ((const float4*)X)[i * 2];
    float4 f1 = ((const float4*)X)[i * 2 + 1];
    uint4 o;
    o.x = (unsigned)f2bf(f0.x) | ((unsigned)f2bf(f0.y) << 16);
    o.y = (unsigned)f2bf(f0.z) | ((unsigned)f2bf(f0.w) << 16);
    o.z = (unsigned)f2bf(f1.x) | ((unsigned)f2bf(f1.y) << 16);
    o.w = (unsigned)f2bf(f1.z) | ((unsigned)f2bf(f1.w) << 16);
    ((uint4*)Xbf)[i] = o;
  }
}

// ---------------------------------------------------------------------------
// Kernel 1 (fast path): Gram partials from bf16 X. grid = 3*nchunk x 512.
// pos = b%3: (0,0),(256,256),(0,256) 256x256 tiles; LDS [c][k] swizzled,
// built by paired-row b32 pack writes.  MFMA operand-swapped; float4 stores.
// ---------------------------------------------------------------------------
__device__ __forceinline__ void stage_pack(const unsigned short* __restrict__ src,
                                           unsigned short* dst, int c0, int k) {
  uint4 a = *(const uint4*)src;          // row k,   cols c0..c0+7
  uint4 b = *(const uint4*)(src + 512);  // row k+1
  unsigned av[4] = {a.x, a.y, a.z, a.w}, bv[4] = {b.x, b.y, b.z, b.w};
  int k7 = (k & 7) * 2, khi = k >> 3;
  #pragma unroll
  for (int j = 0; j < 4; ++j) {
    int cA = c0 + 2 * j, cB = cA + 1;
    unsigned lo = (av[j] & 0xFFFFu) | (bv[j] << 16);
    unsigned hi = (av[j] >> 16) | (bv[j] & 0xFFFF0000u);
    int slA = khi ^ ((cA ^ (cA >> 3)) & 7);
    int slB = khi ^ ((cB ^ (cB >> 3)) & 7);
    *(unsigned*)((char*)dst + cA * 128 + slA * 16 + k7) = lo;
    *(unsigned*)((char*)dst + cB * 128 + slB * 16 + k7) = hi;
  }
}

__global__ __launch_bounds__(512, 2) void gram_bf(
    const unsigned short* __restrict__ Xbf, float* __restrict__ part,
    int nchunk) {
  __shared__ unsigned short As[256 * 64];
  __shared__ unsigned short Bs[256 * 64];
  const int b = blockIdx.x, pos = b % 3, chunk = b / 3;
  const int s0 = (int)((long)4096 * chunk / nchunk);
  const int s1 = (int)((long)4096 * (chunk + 1) / nchunk);
  const int ca = (pos == 1) ? 256 : 0;
  const int cb2 = (pos == 0) ? 0 : 256;
  const bool diag = (pos != 2);
  const int t = threadIdx.x, lane = t & 63, w = t >> 6;
  const int wr = w >> 2, wc = w & 3;

  f32x4 acc[8][4];
  const f32x4 zf = {0.f, 0.f, 0.f, 0.f};
  #pragma unroll
  for (int a = 0; a < 8; ++a)
    #pragma unroll
    for (int bb = 0; bb < 4; ++bb) acc[a][bb] = zf;

  const int c0 = (t & 31) * 8;   // relative col octet
  const int kp = t >> 5;         // 0..15

  for (int ks = s0; ks < s1; ++ks) {
    long rb = (long)ks * 64;
    #pragma unroll
    for (int it = 0; it < 2; ++it) {
      int k = it * 32 + kp * 2;
      long r = rb + k;
      stage_pack(Xbf + r * 512 + ca + c0, As, c0, k);
      if (!diag) stage_pack(Xbf + r * 512 + cb2 + c0, Bs, c0, k);
    }
    __syncthreads();
    const unsigned short* Bp = diag ? As : Bs;
    #pragma unroll
    for (int kk = 0; kk < 2; ++kk) {
      bf16x8 af[8], bfr[4];
      #pragma unroll
      for (int fm = 0; fm < 8; ++fm) {
        int row = wr * 128 + fm * 16 + (lane & 15);
        int slot = swz(row, kk * 4 + (lane >> 4));
        af[fm] = *(const bf16x8*)((const char*)As + row * 128 + slot * 16);
      }
      #pragma unroll
      for (int fn = 0; fn < 4; ++fn) {
        int row = wc * 64 + fn * 16 + (lane & 15);
        int slot = swz(row, kk * 4 + (lane >> 4));
        bfr[fn] = *(const bf16x8*)((const char*)Bp + row * 128 + slot * 16);
      }
      #pragma unroll
      for (int fm = 0; fm < 8; ++fm)
        #pragma unroll
        for (int fn = 0; fn < 4; ++fn)
          acc[fm][fn] = __builtin_amdgcn_mfma_f32_16x16x32_bf16(
              bfr[fn], af[fm], acc[fm][fn], 0, 0, 0);   // swapped: reg axis = n
    }
    __syncthreads();
  }
  float* out = part + (long)b * 65536;
  #pragma unroll
  for (int fm = 0; fm < 8; ++fm)
    #pragma unroll
    for (int fn = 0; fn < 4; ++fn) {
      int mi = wr * 128 + fm * 16 + (lane & 15);
      int nj = wc * 64 + fn * 16 + (lane >> 4) * 4;
      *(float4*)(out + mi * 256 + nj) = *(float4*)&acc[fm][fn];
    }
}

// ---------------------------------------------------------------------------
// Kernel 1b (fallback): Gram partials from fp32 X (round-1 version).
// ---------------------------------------------------------------------------
__global__ __launch_bounds__(512, 2) void gram_f32(
    const float* __restrict__ X, float* __restrict__ part, int nchunk) {
  __shared__ unsigned short As[256 * 64];
  __shared__ unsigned short Bs[256 * 64];
  const int b = blockIdx.x;
  const int pos = b % 3;
  const int chunk = b / 3;
  const int CR = 262144 / nchunk;
  const long r0 = (long)chunk * CR;
  const int ca = (pos == 1) ? 256 : 0;
  const int cb = (pos == 0) ? 0 : 256;
  const bool diag = (pos != 2);
  const int t = threadIdx.x, lane = t & 63, w = t >> 6;
  const int wr = w >> 2, wc = w & 3;

  f32x4 acc[8][4];
  const f32x4 zf = {0.f, 0.f, 0.f, 0.f};
  #pragma unroll
  for (int a = 0; a < 8; ++a)
    #pragma unroll
    for (int bb = 0; bb < 4; ++bb) acc[a][bb] = zf;

  const int c_oct = t & 31, msub = t >> 5;

  for (int ks = 0; ks < CR; ks += 64) {
    #pragma unroll
    for (int it = 0; it < 4; ++it) {
      int m = msub + 16 * it;
      long row = r0 + ks + m;
      const float4* sa = (const float4*)(X + row * 512 + ca + c_oct * 8);
      float4 a0 = sa[0], a1 = sa[1];
      {
        float v[8] = {a0.x, a0.y, a0.z, a0.w, a1.x, a1.y, a1.z, a1.w};
        #pragma unroll
        for (int s = 0; s < 8; ++s) {
          int c = c_oct * 8 + s;
          int off = c * 128 + ((2 * m) ^ (((c ^ (c >> 3)) & 7) << 4));
          *(unsigned short*)((char*)As + off) = f2bf(v[s]);
        }
      }
      if (!diag) {
        const float4* sb = (const float4*)(X + row * 512 + cb + c_oct * 8);
        float4 b0 = sb[0], b1 = sb[1];
        float v[8] = {b0.x, b0.y, b0.z, b0.w, b1.x, b1.y, b1.z, b1.w};
        #pragma unroll
        for (int s = 0; s < 8; ++s) {
          int c = c_oct * 8 + s;
          int off = c * 128 + ((2 * m) ^ (((c ^ (c >> 3)) & 7) << 4));
          *(unsigned short*)((char*)Bs + off) = f2bf(v[s]);
        }
      }
    }
    __syncthreads();
    const unsigned short* Bp = diag ? As : Bs;
    #pragma unroll
    for (int kk = 0; kk < 2; ++kk) {
      bf16x8 af[8], bfr[4];
      #pragma unroll
      for (int fm = 0; fm < 8; ++fm) {
        int row = wr * 128 + fm * 16 + (lane & 15);
        int slot = swz(row, kk * 4 + (lane >> 4));
        af[fm] = *(const bf16x8*)((const char*)As + row * 128 + slot * 16);
      }
      #pragma unroll
      for (int fn = 0; fn < 4; ++fn) {
        int row = wc * 64 + fn * 16 + (lane & 15);
        int slot = swz(row, kk * 4 + (lane >> 4));
        bfr[fn] = *(const bf16x8*)((const char*)Bp + row * 128 + slot * 16);
      }
      #pragma unroll
      for (int fm = 0; fm < 8; ++fm)
        #pragma unroll
        for (int fn = 0; fn < 4; ++fn)
          acc[fm][fn] = __builtin_amdgcn_mfma_f32_16x16x32_bf16(
              af[fm], bfr[fn], acc[fm][fn], 0, 0, 0);
    }
    __syncthreads();
  }
  float* out = part + (long)b * 65536;
  #pragma unroll
  for (int fm = 0; fm < 8; ++fm)
    #pragma unroll
    for (int fn = 0; fn < 4; ++fn)
      #pragma unroll
      for (int j = 0; j < 4; ++j) {
        int i  = wr * 128 + fm * 16 + (lane >> 4) * 4 + j;
        int jj = wc * 64 + fn * 16 + (lane & 15);
        out[i * 256 + jj] = acc[fm][fn][j];
      }
}

// ---------------------------------------------------------------------------
// Kernel 2: reduce partials -> full symmetric G [512][512] fp32. grid 768x256
// ---------------------------------------------------------------------------
__global__ void gram_reduce(const float* __restrict__ part,
                            float* __restrict__ G, int nchunk) {
  int idx = blockIdx.x * 256 + threadIdx.x;   // < 196608
  int pos = idx >> 16;
  int e = idx & 65535;
  float s = 0.f;
  for (int ch = 0; ch < nchunk; ++ch)
    s += part[(long)(ch * 3 + pos) * 65536 + e];
  int i = e >> 8, j = e & 255;
  if (pos == 0) {
    G[i * 512 + j] = s;
  } else if (pos == 1) {
    G[(256 + i) * 512 + 256 + j] = s;
  } else {
    G[i * 512 + 256 + j] = s;
    G[(256 + j) * 512 + i] = s;
  }
}

// ---------------------------------------------------------------------------
// Kernel 3: left-looking diag step, NB=64.  One block, 256 threads.
// 1) Pb = G[p][p] + eps I - sum_{r<p} L[p][r] L[p][r]^T   (LDS-staged SYRK)
// 2) factor Pb (two 32-panels; r[32]/x[32] register patterns)
// 3) Dinv_p = Pb^{-1} via A^{-1},C^{-1} (x[32] column solves) + 2 small GEMMs
// 4) write L[p][p] into G (in place), Dinv_p (full 64x64, exact upper zeros)
// ---------------------------------------------------------------------------
__global__ __launch_bounds__(256) void chol_d64(float* __restrict__ G,
                                                float* __restrict__ Dinv,
                                                int p) {
  __shared__ float Pb[64][65];
  __shared__ float Sb[64][65];
  __shared__ float Inv[64][65];
  __shared__ float Tt[32][33];
  const int t = threadIdx.x;
  const int r0 = 64 * p;
  const int tr = (t >> 4) * 4, tc = (t & 15) * 4;

  for (int idx = t; idx < 4096; idx += 256) {
    int i = idx >> 6, j = idx & 63;
    float v = G[(long)(r0 + i) * 512 + r0 + j];
    if (i == j) v += EPSJ;
    Pb[i][j] = v;
  }
  __syncthreads();

  if (p > 0) {
    float cc[4][4] = {{0.f}};
    for (int r = 0; r < p; ++r) {
      for (int idx = t; idx < 4096; idx += 256) {
        int i = idx >> 6, j = idx & 63;
        Sb[i][j] = G[(long)(r0 + i) * 512 + 64 * r + j];
      }
      __syncthreads();
      #pragma unroll 4
      for (int k = 0; k < 64; ++k) {
        float a0 = Sb[tr][k], a1 = Sb[tr+1][k], a2 = Sb[tr+2][k], a3 = Sb[tr+3][k];
        float b0 = Sb[tc][k], b1 = Sb[tc+1][k], b2 = Sb[tc+2][k], b3 = Sb[tc+3][k];
        cc[0][0]+=a0*b0; cc[0][1]+=a0*b1; cc[0][2]+=a0*b2; cc[0][3]+=a0*b3;
        cc[1][0]+=a1*b0; cc[1][1]+=a1*b1; cc[1][2]+=a1*b2; cc[1][3]+=a1*b3;
        cc[2][0]+=a2*b0; cc[2][1]+=a2*b1; cc[2][2]+=a2*b2; cc[2][3]+=a2*b3;
        cc[3][0]+=a3*b0; cc[3][1]+=a3*b1; cc[3][2]+=a3*b2; cc[3][3]+=a3*b3;
      }
      __syncthreads();
    }
    #pragma unroll
    for (int u = 0; u < 4; ++u)
      #pragma unroll
      for (int v = 0; v < 4; ++v)
        Pb[tr + u][tc + v] -= cc[u][v];
    __syncthreads();
  }

  const int lane = t & 63, w = t >> 6;
  #pragma unroll
  for (int sp = 0; sp < 2; ++sp) {
    const int b0 = sp * 32;
    if (w == 0) {                       // 32-col register factor (proven)
      float rr[32];
      #pragma unroll
      for (int k = 0; k < 32; ++k)
        rr[k] = (lane < 32) ? Pb[b0 + lane][b0 + k] : 0.f;
      #pragma unroll
      for (int j = 0; j < 32; ++j) {
        float d = sqrtf(__shfl(rr[j], j));
        if (lane == j) rr[j] = d;
        else if (lane > j && lane < 32) rr[j] = rr[j] / d;
        float rj = rr[j];
        #pragma unroll
        for (int k = j + 1; k < 32; ++k) {
          float Lkj = __shfl(rj, k);
          if (lane > j && lane < 32) rr[k] -= rj * Lkj;
        }
      }
      #pragma unroll
      for (int k = 0; k < 32; ++k)
        if (lane < 32) Pb[b0 + lane][b0 + k] = rr[k];
    }
    __syncthreads();
    if (sp == 0) {
      if (t < 32) {                     // solve rows 32..63 vs A (proven)
        int rw = 32 + t;
        float x[32];
        #pragma unroll
        for (int j = 0; j < 32; ++j) x[j] = Pb[rw][j];
        #pragma unroll
        for (int j = 0; j < 32; ++j) {
          float xj = x[j] / Pb[j][j];
          x[j] = xj;
          #pragma unroll
          for (int k2 = j + 1; k2 < 32; ++k2) x[k2] -= xj * Pb[k2][j];
        }
        #pragma unroll
        for (int j = 0; j < 32; ++j) Pb[rw][j] = x[j];
      }
      __syncthreads();
      {                                 // trailing 32x32 -= S S^T
        int i = 32 + (t >> 3), kb = 32 + (t & 7) * 4;
        float sv[4];
        #pragma unroll
        for (int e = 0; e < 4; ++e) sv[e] = Pb[i][kb + e];
        #pragma unroll 4
        for (int j = 0; j < 32; ++j) {
          float aij = Pb[i][j];
          #pragma unroll
          for (int e = 0; e < 4; ++e) sv[e] -= aij * Pb[kb + e][j];
        }
        #pragma unroll
        for (int e = 0; e < 4; ++e) Pb[i][kb + e] = sv[e];
      }
      __syncthreads();
    }
  }

  // invert A (0..31) and C (32..63): 64 parallel column solves (x[32])
  if (t < 64) {
    int col = t & 31, o = (t >> 5) * 32;
    float x[32];
    #pragma unroll
    for (int i = 0; i < 32; ++i) {
      float s = (i == col) ? 1.f : 0.f;
      #pragma unroll
      for (int j = 0; j < i; ++j) s -= Pb[o + i][o + j] * x[j];
      x[i] = s / Pb[o + i][o + i];
    }
    #pragma unroll
    for (int i = 0; i < 32; ++i) Inv[o + i][o + col] = x[i];
  }
  for (int idx = t; idx < 1024; idx += 256)      // zero top-right quadrant
    Inv[idx >> 5][32 + (idx & 31)] = 0.f;
  __syncthreads();
  {                                              // T1 = B * A^{-1}
    int i = t >> 3, jb = (t & 7) * 4;
    float sv[4] = {0.f, 0.f, 0.f, 0.f};
    #pragma unroll 4
    for (int k = 0; k < 32; ++k) {
      float bik = Pb[32 + i][k];
      #pragma unroll
      for (int e = 0; e < 4; ++e) sv[e] += bik * Inv[k][jb + e];
    }
    #pragma unroll
    for (int e = 0; e < 4; ++e) Tt[i][jb + e] = sv[e];
  }
  __syncthreads();
  {                                              // BL = -C^{-1} * T1
    int i = t >> 3, jb = (t & 7) * 4;
    float sv[4] = {0.f, 0.f, 0.f, 0.f};
    #pragma unroll 4
    for (int k = 0; k < 32; ++k) {
      float cik = Inv[32 + i][32 + k];
      #pragma unroll
      for (int e = 0; e < 4; ++e) sv[e] += cik * Tt[k][jb + e];
    }
    #pragma unroll
    for (int e = 0; e < 4; ++e) Inv[32 + i][jb + e] = -sv[e];
  }
  __syncthreads();
  for (int idx = t; idx < 4096; idx += 256) {
    int i = idx >> 6, j = idx & 63;
    G[(long)(r0 + i) * 512 + r0 + j] = Pb[i][j];
    Dinv[p * 4096 + idx] = Inv[i][j];
  }
}

// ---------------------------------------------------------------------------
// Kernel 4: left-looking panel trsm-as-GEMM.  grid (7-p) x 256.
// L[i][p] = (G[i][p] - sum_{r<p} L[i][r] L[p][r]^T) * Dinv_p^T
// ---------------------------------------------------------------------------
__global__ __launch_bounds__(256) void chol_t64(float* __restrict__ G,
                                                const float* __restrict__ Dinv,
                                                int p) {
  __shared__ float SbI[64][65];
  __shared__ float SbP[64][65];
  __shared__ float Ub[64][65];
  __shared__ float Db[64][65];
  const int t = threadIdx.x;
  const long rI = 64 * (p + 1 + blockIdx.x), cP = 64 * p;
  const int tr = (t >> 4) * 4, tc = (t & 15) * 4;

  for (int idx = t; idx < 4096; idx += 256)
    Db[idx >> 6][idx & 63] = Dinv[p * 4096 + idx];

  float cc[4][4] = {{0.f}};
  for (int r = 0; r < p; ++r) {
    __syncthreads();
    for (int idx = t; idx < 4096; idx += 256) {
      int i = idx >> 6, j = idx & 63;
      SbI[i][j] = G[(rI + i) * 512 + 64 * r + j];
      SbP[i][j] = G[(cP + i) * 512 + 64 * r + j];
    }
    __syncthreads();
    #pragma unroll 4
    for (int k = 0; k < 64; ++k) {
      float a0 = SbI[tr][k], a1 = SbI[tr+1][k], a2 = SbI[tr+2][k], a3 = SbI[tr+3][k];
      float b0 = SbP[tc][k], b1 = SbP[tc+1][k], b2 = SbP[tc+2][k], b3 = SbP[tc+3][k];
      cc[0][0]+=a0*b0; cc[0][1]+=a0*b1; cc[0][2]+=a0*b2; cc[0][3]+=a0*b3;
      cc[1][0]+=a1*b0; cc[1][1]+=a1*b1; cc[1][2]+=a1*b2; cc[1][3]+=a1*b3;
      cc[2][0]+=a2*b0; cc[2][1]+=a2*b1; cc[2][2]+=a2*b2; cc[2][3]+=a2*b3;
      cc[3][0]+=a3*b0; cc[3][1]+=a3*b1; cc[3][2]+=a3*b2; cc[3][3]+=a3*b3;
    }
  }
  __syncthreads();
  #pragma unroll
  for (int u = 0; u < 4; ++u)
    #pragma unroll
    for (int v = 0; v < 4; ++v)
      Ub[tr + u][tc + v] =
          G[(rI + tr + u) * 512 + cP + tc + v] - cc[u][v];
  __syncthreads();
  float xx[4][4] = {{0.f}};
  #pragma unroll 4
  for (int k = 0; k < 64; ++k) {
    float a0 = Ub[tr][k], a1 = Ub[tr+1][k], a2 = Ub[tr+2][k], a3 = Ub[tr+3][k];
    float b0 = Db[tc][k], b1 = Db[tc+1][k], b2 = Db[tc+2][k], b3 = Db[tc+3][k];
    xx[0][0]+=a0*b0; xx[0][1]+=a0*b1; xx[0][2]+=a0*b2; xx[0][3]+=a0*b3;
    xx[1][0]+=a1*b0; xx[1][1]+=a1*b1; xx[1][2]+=a1*b2; xx[1][3]+=a1*b3;
    xx[2][0]+=a2*b0; xx[2][1]+=a2*b1; xx[2][2]+=a2*b2; xx[2][3]+=a2*b3;
    xx[3][0]+=a3*b0; xx[3][1]+=a3*b1; xx[3][2]+=a3*b2; xx[3][3]+=a3*b3;
  }
  #pragma unroll
  for (int u = 0; u < 4; ++u)
    #pragma unroll
    for (int v = 0; v < 4; ++v)
      G[(rI + tr + u) * 512 + cP + tc + v] = xx[u][v];
}

// ---------------------------------------------------------------------------
// Kernel 5: blocked back-substitution, one workgroup per 64-wide column
// block q of Linv: B_p = -Dinv_p * sum_{r=q}^{p-1} L[p,r] B_r  (B_q = Dinv_q).
// Emits Wt[n][k] = sqrt(512)*Linv[n][k] bf16, slot-pre-swizzled for ymm2,
// plus zeros for the upper triangle.  grid 8 x 256.
// ---------------------------------------------------------------------------
__global__ __launch_bounds__(256) void tri_assemble(
    const float* __restrict__ G, const float* __restrict__ Dinv,
    unsigned short* __restrict__ Wt) {
  __shared__ float Bsh[448 * 64];   // rows for p>q, 112 KB
  __shared__ float T[64 * 64];      // 16 KB
  const int q = blockIdx.x, t = threadIdx.x;
  const int or_ = (t >> 4) * 4, oc = (t & 15) * 4;

  for (int p = q + 1; p < 8; ++p) {
    float cc[4][4] = {{0.f}};
    for (int r = q; r < p; ++r) {
      const float* Lbase = G + (long)(64 * p) * 512 + 64 * r;
      #pragma unroll 4
      for (int k = 0; k < 64; ++k) {
        float a0 = Lbase[(or_ + 0) * 512 + k];
        float a1 = Lbase[(or_ + 1) * 512 + k];
        float a2 = Lbase[(or_ + 2) * 512 + k];
        float a3 = Lbase[(or_ + 3) * 512 + k];
        float b0, b1, b2, b3;
        if (r == q) {
          const float* Bq = Dinv + q * 4096 + k * 64 + oc;
          b0 = Bq[0]; b1 = Bq[1]; b2 = Bq[2]; b3 = Bq[3];
        } else {
          const float* Br = Bsh + ((r - q - 1) * 64 + k) * 64 + oc;
          b0 = Br[0]; b1 = Br[1]; b2 = Br[2]; b3 = Br[3];
        }
        cc[0][0] += a0*b0; cc[0][1] += a0*b1; cc[0][2] += a0*b2; cc[0][3] += a0*b3;
        cc[1][0] += a1*b0; cc[1][1] += a1*b1; cc[1][2] += a1*b2; cc[1][3] += a1*b3;
        cc[2][0] += a2*b0; cc[2][1] += a2*b1; cc[2][2] += a2*b2; cc[2][3] += a2*b3;
        cc[3][0] += a3*b0; cc[3][1] += a3*b1; cc[3][2] += a3*b2; cc[3][3] += a3*b3;
      }
    }
    #pragma unroll
    for (int u = 0; u < 4; ++u)
      #pragma unroll
      for (int v = 0; v < 4; ++v)
        T[(or_ + u) * 64 + oc + v] = cc[u][v];
    __syncthreads();

    float c2[4][4] = {{0.f}};
    const float* Dp = Dinv + p * 4096;
    #pragma unroll 4
    for (int k = 0; k < 64; ++k) {
      float a0 = Dp[(or_ + 0) * 64 + k];
      float a1 = Dp[(or_ + 1) * 64 + k];
      float a2 = Dp[(or_ + 2) * 64 + k];
      float a3 = Dp[(or_ + 3) * 64 + k];
      const float* Tk = T + k * 64 + oc;
      float b0 = Tk[0], b1 = Tk[1], b2 = Tk[2], b3 = Tk[3];
      c2[0][0] += a0*b0; c2[0][1] += a0*b1; c2[0][2] += a0*b2; c2[0][3] += a0*b3;
      c2[1][0] += a1*b0; c2[1][1] += a1*b1; c2[1][2] += a1*b2; c2[1][3] += a1*b3;
      c2[2][0] += a2*b0; c2[2][1] += a2*b1; c2[2][2] += a2*b2; c2[2][3] += a2*b3;
      c2[3][0] += a3*b0; c2[3][1] += a3*b1; c2[3][2] += a3*b2; c2[3][3] += a3*b3;
    }
    #pragma unroll
    for (int u = 0; u < 4; ++u)
      #pragma unroll
      for (int v = 0; v < 4; ++v)
        Bsh[((p - q - 1) * 64 + or_ + u) * 64 + oc + v] = -c2[u][v];
    __syncthreads();
  }

  const int nr = (8 - q) * 64;
  for (int idx = t; idx < nr * 64; idx += 256) {
    int i = idx >> 6, kk = idx & 63;
    float v = (i < 64) ? Dinv[q * 4096 + i * 64 + kk]
                       : Bsh[(i - 64) * 64 + kk];
    int n = 64 * q + i;
    int sl = (kk >> 3) ^ ((n ^ (n >> 3)) & 7);
    Wt[(long)n * 512 + 64 * q + sl * 8 + (kk & 7)] = f2bf(SQRTD * v);
  }
  for (int idx = t; idx < 64 * q * 64; idx += 256) {   // zeros above diagonal
    int n = idx >> 6, kk = idx & 63;
    Wt[(long)n * 512 + 64 * q + kk] = 0;
  }
}

// ---------------------------------------------------------------------------
// Kernel 5b (fallback): wave-per-column triangular inverse, plain Wt layout.
// ---------------------------------------------------------------------------
__global__ void tri_inv(const float* __restrict__ G,
                        unsigned short* __restrict__ Wt) {
  int w = threadIdx.x >> 6, lane = threadIdx.x & 63;
  int c = blockIdx.x * 4 + w;
  float v8[8];
  #pragma unroll
  for (int q = 0; q < 8; ++q) v8[q] = 0.f;
  #pragma unroll
  for (int q = 0; q < 8; ++q) {
    for (int ii = 0; ii < 64; ++ii) {
      int i = q * 64 + ii;
      const float* Lrow = G + (long)i * 512;
      float s = 0.f;
      #pragma unroll
      for (int qq = 0; qq < 8; ++qq) {
        if (qq < q) s += v8[qq] * Lrow[qq * 64 + lane];
      }
      s += (lane < ii) ? v8[q] * Lrow[q * 64 + lane] : 0.f;
      s = wred(s);
      float xi = (((i == c) ? 1.f : 0.f) - s) / Lrow[i];
      if (lane == ii) v8[q] = xi;
    }
  }
  #pragma unroll
  for (int q = 0; q < 8; ++q) {
    int i = q * 64 + lane;
    Wt[(long)i * 512 + c] = f2bf(SQRTD * v8[q]);
  }
}

// ---------------------------------------------------------------------------
// Kernel 6 (fast path): Y = Xbf @ W via global_load_lds staging, dbuf.
// grid (4 n, 2048 m) x 256.  MFMA operand-swapped -> float4 C stores.
// ---------------------------------------------------------------------------
__global__ __launch_bounds__(256, 2) void ymm2(
    const unsigned short* __restrict__ Xbf,
    const unsigned short* __restrict__ Wt, float* __restrict__ Y) {
  __shared__ unsigned short As[2][128 * 64];
  __shared__ unsigned short Bs[2][128 * 64];
  const int t = threadIdx.x, lane = t & 63, w = t >> 6;
  const long m0 = (long)blockIdx.y * 128;
  const int n0 = blockIdx.x * 128;
  const int wm = (w >> 1) * 64, wn = (w & 1) * 64;
  const int lrow = lane >> 3, lslot = lane & 7;
  f32x4 acc[4][4];
  const f32x4 zf = {0.f, 0.f, 0.f, 0.f};
  #pragma unroll
  for (int a = 0; a < 4; ++a)
    #pragma unroll
    for (int bq = 0; bq < 4; ++bq) acc[a][bq] = zf;

  auto stage = [&](int buf, int k0) {
    #pragma unroll
    for (int j = 0; j < 4; ++j) {
      int row = (w * 4 + j) * 8 + lrow;
      const unsigned short* sA =
          Xbf + (m0 + row) * 512 + k0 + swz(row, lslot) * 8;
      const unsigned short* sB =
          Wt + (long)(n0 + row) * 512 + k0 + lslot * 8;
      GLOAD16(sA, &As[buf][(w * 4 + j) * 512]);
      GLOAD16(sB, &Bs[buf][(w * 4 + j) * 512]);
    }
  };
  auto compute = [&](int buf) {
    #pragma unroll
    for (int kk = 0; kk < 2; ++kk) {
      bf16x8 af[4], bfr[4];
      #pragma unroll
      for (int fm = 0; fm < 4; ++fm) {
        int row = wm + fm * 16 + (lane & 15);
        af[fm] = *(const bf16x8*)((const char*)As[buf] + row * 128 +
                                  swz(row, kk * 4 + (lane >> 4)) * 16);
      }
      #pragma unroll
      for (int fn = 0; fn < 4; ++fn) {
        int row = wn + fn * 16 + (lane & 15);
        bfr[fn] = *(const bf16x8*)((const char*)Bs[buf] + row * 128 +
                                   swz(row, kk * 4 + (lane >> 4)) * 16);
      }
      #pragma unroll
      for (int fm = 0; fm < 4; ++fm)
        #pragma unroll
        for (int fn = 0; fn < 4; ++fn)
          acc[fm][fn] = __builtin_amdgcn_mfma_f32_16x16x32_bf16(
              bfr[fn], af[fm], acc[fm][fn], 0, 0, 0);   // swapped
    }
  };

  stage(0, 0);
  __syncthreads();
  int cur = 0;
  #pragma unroll 1
  for (int kt = 0; kt < 7; ++kt) {
    stage(cur ^ 1, (kt + 1) * 64);
    compute(cur);
    __syncthreads();
    cur ^= 1;
  }
  compute(cur);

  #pragma unroll
  for (int fm = 0; fm < 4; ++fm)
    #pragma unroll
    for (int fn = 0; fn < 4; ++fn) {
      long row = m0 + wm + fm * 16 + (lane & 15);
      int col = n0 + wn + fn * 16 + (lane >> 4) * 4;
      *(float4*)(Y + row * 512 + col) = *(float4*)&acc[fm][fn];
    }
}

// ---------------------------------------------------------------------------
// Kernel 6b (fallback): round-1 ymm, fp32 X reg-staged, plain Wt.
// ---------------------------------------------------------------------------
__global__ __launch_bounds__(256) void ymm_v1(const float* __restrict__ X,
                                              const unsigned short* __restrict__ Wt,
                                              float* __restrict__ Y) {
  __shared__ unsigned short As[128 * 64];
  __shared__ unsigned short Bs[128 * 64];
  const int t = threadIdx.x, lane = t & 63, w = t >> 6;
  const long m0 = (long)blockIdx.x * 128;
  const int n0 = blockIdx.y * 128;
  const int wm = (w >> 1) * 64, wn = (w & 1) * 64;
  f32x4 acc[4][4];
  const f32x4 zf = {0.f, 0.f, 0.f, 0.f};
  #pragma unroll
  for (int a = 0; a < 4; ++a)
    #pragma unroll
    for (int bq = 0; bq < 4; ++bq) acc[a][bq] = zf;
  const int ko = t & 7, mrow = t >> 3;

  for (int k0 = 0; k0 < 512; k0 += 64) {
    #pragma unroll
    for (int it = 0; it < 4; ++it) {
      int m = mrow + 32 * it;
      const float4* src = (const float4*)(X + (m0 + m) * 512 + k0 + ko * 8);
      float4 f0 = src[0], f1 = src[1];
      unsigned p0 = (unsigned)f2bf(f0.x) | ((unsigned)f2bf(f0.y) << 16);
      unsigned p1 = (unsigned)f2bf(f0.z) | ((unsigned)f2bf(f0.w) << 16);
      unsigned p2 = (unsigned)f2bf(f1.x) | ((unsigned)f2bf(f1.y) << 16);
      unsigned p3 = (unsigned)f2bf(f1.z) | ((unsigned)f2bf(f1.w) << 16);
      int slot = swz(m, ko);
      *(uint4*)((char*)As + m * 128 + slot * 16) = make_uint4(p0, p1, p2, p3);
    }
    #pragma unroll
    for (int it = 0; it < 4; ++it) {
      int n = mrow + 32 * it;
      uint4 raw = *(const uint4*)(Wt + (long)(n0 + n) * 512 + k0 + ko * 8);
      int slot = swz(n, ko);
      *(uint4*)((char*)Bs + n * 128 + slot * 16) = raw;
    }
    __syncthreads();
    #pragma unroll
    for (int kk = 0; kk < 2; ++kk) {
      bf16x8 af[4], bfr[4];
      #pragma unroll
      for (int fm = 0; fm < 4; ++fm) {
        int row = wm + fm * 16 + (lane & 15);
        af[fm] = *(const bf16x8*)((const char*)As + row * 128 +
                                  swz(row, kk * 4 + (lane >> 4)) * 16);
      }
      #pragma unroll
      for (int fn = 0; fn < 4; ++fn) {
        int row = wn + fn * 16 + (lane & 15);
        bfr[fn] = *(const bf16x8*)((const char*)Bs + row * 128 +
                                   swz(row, kk * 4 + (lane >> 4)) * 16);
      }
      #pragma unroll
      for (int fm = 0; fm < 4; ++fm)
        #pragma unroll
        for (int fn = 0; fn < 4; ++fn)
          acc[fm][fn] = __builtin_amdgcn_mfma_f32_16x16x32_bf16(
              af[fm], bfr[fn], acc[fm][fn], 0, 0, 0);
    }
    __syncthreads();
  }
  #pragma unroll
  for (int fm = 0; fm < 4; ++fm)
    #pragma unroll
    for (int fn = 0; fn < 4; ++fn)
      #pragma unroll
      for (int j = 0; j < 4; ++j) {
        long row = m0 + wm + fm * 16 + (lane >> 4) * 4 + j;
        int col = n0 + wn + fn * 16 + (lane & 15);
        Y[row * 512 + col] = acc[fm][fn][j];
      }
}

// ---------------------------------------------------------------------------
static void chol_chain(float* G, float* Dinv, hipStream_t stream) {
  for (int p = 0; p < 8; ++p) {
    chol_d64<<<1, 256, 0, stream>>>(G, Dinv, p);
    if (p < 7) chol_t64<<<7 - p, 256, 0, stream>>>(G, Dinv, p);
  }
}

extern "C" void kernel_launch(void* const* d_in, const int* in_sizes, int n_in,
                              void* d_out, int out_size, void* d_ws, size_t ws_size,
                              hipStream_t stream) {
  const float* X = (const float*)d_in[0];
  float* Y = (float*)d_out;
  char* ws = (char*)d_ws;
  float* G = (float*)ws;                                     // 1 MiB fp32
  unsigned short* Wt = (unsigned short*)(ws + (1 << 20));    // 512 KiB bf16
  float* Dinv = (float*)(ws + (1 << 20) + (1 << 19));        // 128 KiB fp32

  const int NCH_FAST = 85;
  size_t part_off = (size_t)(2 << 20);
  size_t part_bytes = (size_t)NCH_FAST * 3 * 65536 * 4;      // 66.8 MB
  size_t xbf_off = part_off + part_bytes;
  size_t need = xbf_off + (size_t)134217728 * 2;             // + 256 MiB

  if (ws_size >= need) {
    float* part = (float*)(ws + part_off);
    unsigned short* Xbf = (unsigned short*)(ws + xbf_off);
    convert_bf<<<2048, 256, 0, stream>>>(X, Xbf);
    gram_bf<<<3 * NCH_FAST, 512, 0, stream>>>(Xbf, part, NCH_FAST);
    gram_reduce<<<768, 256, 0, stream>>>(part, G, NCH_FAST);
    chol_chain(G, Dinv, stream);
    tri_assemble<<<8, 256, 0, stream>>>(G, Dinv, Wt);
    ymm2<<<dim3(4, 2048), 256, 0, stream>>>(Xbf, Wt, Y);
  } else {
    float* part = (float*)(ws + part_off);
    size_t fixed = part_off;
    int nchunk = 64;
    while (nchunk > 1 && fixed + (size_t)nchunk * 3 * 65536 * 4 > ws_size)
      nchunk >>= 1;
    gram_f32<<<3 * nchunk, 512, 0, stream>>>(X, part, nchunk);
    gram_reduce<<<768, 256, 0, stream>>>(part, G, nchunk);
    chol_chain(G, Dinv, stream);
    tri_inv<<<128, 256, 0, stream>>>(G, Wt);
    ymm_v1<<<dim3(2048, 4), 256, 0, stream>>>(X, Wt, Y);
  }
}